// Round 7
// baseline (216.703 us; speedup 1.0000x reference)
//
#include <hip/hip_runtime.h>
#include <hip/hip_bf16.h>
#include <stdint.h>

// MultiHeadAttention: B=2, P=2048, D_MODEL=1024, H=16, D=64, causal.
//
// R18: (a) gemm128_core reverted to R15 (single __syncthreads, prefetch-
// before-compute) — R17's sched_barrier(0)+double-barrier was the m141
// regression (qkv 63->84). Used by out_gemm only. (b) NEW qkv_gemm256_k:
// 256x256 tile, BK=64, 8 waves, 128KB dynamic LDS, 4 phases/K-tile with
// half-tile-granular staging (1 batch = 2 gloads/wave per phase) and
// counted vmcnt (2 at p0, 4 at p2; 0 only in the last tile) — the T3+T4
// structure that gives loads a 2-4 phase landing window with one barrier
// per phase and no sched pinning. (c) attn_k unchanged from R16.

typedef __bf16 bf16x8 __attribute__((ext_vector_type(8)));
typedef float f32x4 __attribute__((ext_vector_type(4)));
typedef float f32x16 __attribute__((ext_vector_type(16)));
typedef unsigned short u16;

__device__ __forceinline__ u16 f2bf(float f) {
  unsigned u = __float_as_uint(f);
  u += 0x7fffu + ((u >> 16) & 1u);
  return (u16)(u >> 16);
}

__device__ __forceinline__ uint32_t cvtpk(float lo, float hi) {
  uint32_t r;
  asm("v_cvt_pk_bf16_f32 %0, %1, %2" : "=v"(r) : "v"(lo), "v"(hi));
  return r;
}

__device__ __forceinline__ void pl32swap(uint32_t& a, uint32_t& b) {
  asm volatile("v_permlane32_swap_b32 %0, %1" : "+v"(a), "+v"(b));
}

// ---- X f32 -> bf16 (coalesced, 8 elems/thread) ----
__global__ __launch_bounds__(256) void xcvt_k(const float* __restrict__ in,
                                              u16* __restrict__ out) {
  int i = (blockIdx.x * 256 + threadIdx.x) * 8;
  float4 f0 = *reinterpret_cast<const float4*>(in + i);
  float4 f1 = *reinterpret_cast<const float4*>(in + i + 4);
  u16 tmp[8] = {f2bf(f0.x), f2bf(f0.y), f2bf(f0.z), f2bf(f0.w),
                f2bf(f1.x), f2bf(f1.y), f2bf(f1.z), f2bf(f1.w)};
  *reinterpret_cast<uint4*>(out + i) = *reinterpret_cast<uint4*>(tmp);
}

// ---- generic weight transpose+convert: in f32 [B][R][C] -> out bf16 [B][C][R] ----
__global__ __launch_bounds__(256) void transpose_cvt_k(const float* __restrict__ in,
                                                       u16* __restrict__ out,
                                                       int R, int C) {
  __shared__ u16 tile[64][80];
  int b = blockIdx.z;
  int r0 = blockIdx.x * 64, c0 = blockIdx.y * 64;
  const float* ip = in + (size_t)b * R * C;
  u16* op = out + (size_t)b * R * C;
  int t = threadIdx.x;
  int r = t >> 2, cb = (t & 3) * 16;
  const float4* src = reinterpret_cast<const float4*>(ip + (size_t)(r0 + r) * C + c0 + cb);
  u16 tmp[16];
#pragma unroll
  for (int v = 0; v < 4; v++) {
    float4 f = src[v];
    tmp[v * 4 + 0] = f2bf(f.x);
    tmp[v * 4 + 1] = f2bf(f.y);
    tmp[v * 4 + 2] = f2bf(f.z);
    tmp[v * 4 + 3] = f2bf(f.w);
  }
  *reinterpret_cast<uint4*>(&tile[r][cb]) = *reinterpret_cast<uint4*>(&tmp[0]);
  *reinterpret_cast<uint4*>(&tile[r][cb + 8]) = *reinterpret_cast<uint4*>(&tmp[8]);
  __syncthreads();
  int c = t >> 2, rb = (t & 3) * 16;
  uint4 outv[2];
  u16* tp = reinterpret_cast<u16*>(outv);
#pragma unroll
  for (int j = 0; j < 16; j++) tp[j] = tile[rb + j][c];
  uint4* dst = reinterpret_cast<uint4*>(op + (size_t)(c0 + c) * R + r0 + rb);
  dst[0] = outv[0];
  dst[1] = outv[1];
}

// ---- fused q/k/v weight transpose: z = 0..47 -> (sel = z>>4, head = z&15) ----
__global__ __launch_bounds__(256) void transpose_qkv_k(const float* __restrict__ Wq,
                                                       const float* __restrict__ Wk,
                                                       const float* __restrict__ Wv,
                                                       u16* __restrict__ outBase) {
  __shared__ u16 tile[64][80];
  int z = blockIdx.z;
  int sel = z >> 4, head = z & 15;
  const float* W = (sel == 0) ? Wq : (sel == 1 ? Wk : Wv);
  const float* ip = W + (size_t)head * 65536;           // [1024][64]
  u16* op = outBase + (size_t)sel * 1048576 + (size_t)head * 65536;  // [64][1024]
  int r0 = blockIdx.x * 64;                              // row block in R=1024
  int t = threadIdx.x;
  int r = t >> 2, cb = (t & 3) * 16;
  const float4* src = reinterpret_cast<const float4*>(ip + (size_t)(r0 + r) * 64 + cb);
  u16 tmp[16];
#pragma unroll
  for (int v = 0; v < 4; v++) {
    float4 f = src[v];
    tmp[v * 4 + 0] = f2bf(f.x);
    tmp[v * 4 + 1] = f2bf(f.y);
    tmp[v * 4 + 2] = f2bf(f.z);
    tmp[v * 4 + 3] = f2bf(f.w);
  }
  *reinterpret_cast<uint4*>(&tile[r][cb]) = *reinterpret_cast<uint4*>(&tmp[0]);
  *reinterpret_cast<uint4*>(&tile[r][cb + 8]) = *reinterpret_cast<uint4*>(&tmp[8]);
  __syncthreads();
  int c = t >> 2, rb = (t & 3) * 16;
  uint4 outv[2];
  u16* tp = reinterpret_cast<u16*>(outv);
#pragma unroll
  for (int j = 0; j < 16; j++) tp[j] = tile[rb + j][c];
  uint4* dst = reinterpret_cast<uint4*>(op + (size_t)c * 1024 + r0 + rb);
  dst[0] = outv[0];
  dst[1] = outv[1];
}

// ---- direct global->LDS DMA, 16B per lane (dest = wave-uniform base + lane*16) ----
__device__ __forceinline__ void gload16(const u16* g, u16* l) {
  __builtin_amdgcn_global_load_lds(
      (__attribute__((address_space(1))) void*)(g),
      (__attribute__((address_space(3))) void*)(l), 16, 0, 0);
}

// ====== 128x128 GEMM core (R15 structure): dbuf, single-barrier prefetch ======
// Swizzle (rule #21): 16B chunk p at row r holds global chunk p ^ (r&7);
// stage pre-swizzles the per-lane SOURCE col, reads XOR their chunk index.
__device__ __forceinline__ void gemm128_core(const u16* __restrict__ A,
                                             const u16* __restrict__ BT,
                                             int m0, int n0,
                                             f32x4 (&acc)[4][4]) {
  __shared__ __align__(16) u16 As[2][128][64];
  __shared__ __align__(16) u16 Bs[2][128][64];
  int t = threadIdx.x, l = t & 63;
  int w = t >> 6, wm = w & 1, wn = w >> 1;
  int l15 = l & 15, q4 = l >> 4;
  int r8 = l >> 3;
  int cs = ((l & 7) ^ r8) * 8;
  int swz = l15 & 7;
  int srow = w * 32 + r8;
  const u16* ga = A + (size_t)(m0 + srow) * 1024 + cs;
  const u16* gb = BT + (size_t)(n0 + srow) * 1024 + cs;
  f32x4 z4 = {0.f, 0.f, 0.f, 0.f};
#pragma unroll
  for (int mi = 0; mi < 4; mi++)
#pragma unroll
    for (int nt = 0; nt < 4; nt++) acc[mi][nt] = z4;

#pragma unroll
  for (int i = 0; i < 4; i++) {
    gload16(ga + (size_t)(i * 8) * 1024, &As[0][w * 32 + i * 8][0]);
    gload16(gb + (size_t)(i * 8) * 1024, &Bs[0][w * 32 + i * 8][0]);
  }
  __syncthreads();

  for (int step = 0; step < 16; step++) {
    int cur = step & 1;
    if (step < 15) {
      int k0 = (step + 1) * 64;
#pragma unroll
      for (int i = 0; i < 4; i++) {
        gload16(ga + (size_t)(i * 8) * 1024 + k0, &As[cur ^ 1][w * 32 + i * 8][0]);
        gload16(gb + (size_t)(i * 8) * 1024 + k0, &Bs[cur ^ 1][w * 32 + i * 8][0]);
      }
    }
#pragma unroll
    for (int kk = 0; kk < 2; kk++) {
      bf16x8 af[4], bfr[4];
#pragma unroll
      for (int mi = 0; mi < 4; mi++)
        af[mi] = *reinterpret_cast<const bf16x8*>(
            &As[cur][wm * 64 + mi * 16 + l15][((kk * 4 + q4) ^ swz) * 8]);
#pragma unroll
      for (int nt = 0; nt < 4; nt++)
        bfr[nt] = *reinterpret_cast<const bf16x8*>(
            &Bs[cur][wn * 64 + nt * 16 + l15][((kk * 4 + q4) ^ swz) * 8]);
#pragma unroll
      for (int mi = 0; mi < 4; mi++)
#pragma unroll
        for (int nt = 0; nt < 4; nt++)
          acc[mi][nt] = __builtin_amdgcn_mfma_f32_16x16x32_bf16(af[mi], bfr[nt], acc[mi][nt], 0, 0, 0);
    }
    __syncthreads();
  }
}

// ====== 256x256 QKV GEMM: 4 phases/K-tile, half-tile staging, counted vmcnt ======
// 512 threads = 8 waves (2M x 4N); per-wave output 128x64 (8x4 frags).
// LDS: As[2][256][64] + Bs[2][256][64] = 128KB (dynamic). Tile T reads
// buf[T&1]; during T's 4 phases, tile T+1 is staged into buf[(T+1)&1]
// (fully read as of tile T-1's end => safe after each phase's barrier).
// Staging batches (2 gloads/wave each, FIFO): p0: B-half0, p1: B-half1,
// p2: A-quarters{0,2}, p3: A-quarters{1,3}. Waits: p0 vmcnt(2) [through
// prev p2 batch => B halves + A q0/q2 landed], p2 vmcnt(4) [prev p3 =>
// A q1/q3 landed]; last tile p2 uses vmcnt(0). One s_barrier per phase,
// no sched_barrier (m141), setprio around MFMA (T5).
__global__ __launch_bounds__(512, 1) void qkv_gemm256_k(const u16* __restrict__ A,
                                                        const u16* __restrict__ BT,
                                                        u16* __restrict__ Q,
                                                        u16* __restrict__ K,
                                                        u16* __restrict__ VT2) {
  extern __shared__ __align__(16) u16 sm[];
  u16* As = sm;                      // [2][256][64]
  u16* Bs = sm + 2 * 256 * 64;       // [2][256][64]
  const float QSCALE = 0.125f * 1.44269504088896340736f;  // (1/sqrt(64))*log2(e)
  int m0 = blockIdx.x * 256, n0 = blockIdx.y * 256;
  int t = threadIdx.x, l = t & 63, w = t >> 6;   // w 0..7
  int wm = w >> 2, wn = w & 3;
  int l15 = l & 15, q4 = l >> 4;
  int r8 = l >> 3;
  int cs = ((l & 7) ^ r8) * 8;       // pre-swizzled source chunk
  int swz = l15 & 7;                 // read-side XOR key
  const u16* gA = A + (size_t)m0 * 1024 + cs;
  const u16* gB = BT + (size_t)n0 * 1024 + cs;

  f32x4 acc[8][4];
  f32x4 z4 = {0.f, 0.f, 0.f, 0.f};
#pragma unroll
  for (int mi = 0; mi < 8; mi++)
#pragma unroll
    for (int nt = 0; nt < 4; nt++) acc[mi][nt] = z4;

  // staging helpers (each = 2 gload16 per wave)
  auto stageB = [&](int buf, int h, int kcol) {
#pragma unroll
    for (int j = 0; j < 2; j++) {
      int row = 128 * h + w * 16 + j * 8;          // + r8 per-lane
      gload16(gB + (size_t)(row + r8) * 1024 + kcol,
              &Bs[((size_t)buf * 256 + row) * 64]);
    }
  };
  auto stageA2 = [&](int buf, int qsel, int kcol) {  // quarters {qsel, qsel+2}
#pragma unroll
    for (int j = 0; j < 2; j++) {
      int qq = qsel + 2 * j;
      int row = 64 * qq + w * 8;                    // + r8 per-lane
      gload16(gA + (size_t)(row + r8) * 1024 + kcol,
              &As[((size_t)buf * 256 + row) * 64]);
    }
  };

  // prologue = virtual tile -1 phases: stage tile 0 into buf 0, batch order
  // B-h0, B-h1, A-q{0,2}, A-q{1,3} (must match in-loop order for FIFO waits)
  stageB(0, 0, 0);
  stageB(0, 1, 0);
  stageA2(0, 0, 0);
  stageA2(0, 1, 0);

  for (int T = 0; T < 16; T++) {
    int buf = T & 1, nbuf = buf ^ 1;
    int nk = (T + 1) * 64;
    bool more = T < 15;
    bf16x8 bfr[4][2];
#pragma unroll
    for (int p = 0; p < 4; p++) {
      // ---- counted wait (FIFO over 2-gload batches), then rendezvous ----
      if (p == 0) {
        asm volatile("s_waitcnt vmcnt(2)" ::: "memory");
      } else if (p == 2) {
        if (more)
          asm volatile("s_waitcnt vmcnt(4)" ::: "memory");
        else
          asm volatile("s_waitcnt vmcnt(0)" ::: "memory");
      }
      __builtin_amdgcn_s_barrier();
      // ---- stage one batch for tile T+1 (after barrier: T-1 reads done) ----
      if (more) {
        if (p == 0) stageB(nbuf, 0, nk);
        else if (p == 1) stageB(nbuf, 1, nk);
        else if (p == 2) stageA2(nbuf, 0, nk);
        else stageA2(nbuf, 1, nk);
      }
      // ---- B fragments: hoisted once per tile at phase 0 ----
      if (p == 0) {
#pragma unroll
        for (int nt = 0; nt < 4; nt++) {
          int row = wn * 64 + nt * 16 + l15;
#pragma unroll
          for (int kk = 0; kk < 2; kk++)
            bfr[nt][kk] = *reinterpret_cast<const bf16x8*>(
                &Bs[((size_t)buf * 256 + row) * 64 + ((kk * 4 + q4) ^ swz) * 8]);
        }
      }
      // ---- A fragments for this phase's two mi rows ----
      bf16x8 af[2][2];
#pragma unroll
      for (int j = 0; j < 2; j++) {
        int mi = 2 * p + j;
        int row = wm * 128 + mi * 16 + l15;
#pragma unroll
        for (int kk = 0; kk < 2; kk++)
          af[j][kk] = *reinterpret_cast<const bf16x8*>(
              &As[((size_t)buf * 256 + row) * 64 + ((kk * 4 + q4) ^ swz) * 8]);
      }
      // ---- 16 MFMA ----
      __builtin_amdgcn_s_setprio(1);
#pragma unroll
      for (int kk = 0; kk < 2; kk++)
#pragma unroll
        for (int j = 0; j < 2; j++)
#pragma unroll
          for (int nt = 0; nt < 4; nt++)
            acc[2 * p + j][nt] = __builtin_amdgcn_mfma_f32_16x16x32_bf16(
                af[j][kk], bfr[nt][kk], acc[2 * p + j][nt], 0, 0, 0);
      __builtin_amdgcn_s_setprio(0);
    }
  }

  // ---- epilogue: Q/K scaled bf16, V tile-blocked ----
#pragma unroll
  for (int mi = 0; mi < 8; mi++) {
#pragma unroll
    for (int nt = 0; nt < 4; nt++) {
#pragma unroll
      for (int r = 0; r < 4; r++) {
        int m = m0 + wm * 128 + mi * 16 + q4 * 4 + r;
        int n = n0 + wn * 64 + nt * 16 + l15;
        int wsel = n >> 10, h = (n >> 6) & 15, d = n & 63;
        int b = m >> 11, p = m & 2047;
        size_t bh = (size_t)(b * 16 + h);
        float v = acc[mi][nt][r];
        if (wsel == 0)
          Q[(bh * 2048 + p) * 64 + d] = f2bf(v * QSCALE);
        else if (wsel == 1)
          K[(bh * 2048 + p) * 64 + d] = f2bf(v);
        else
          VT2[((bh * 32 + (p >> 6)) * 64 + d) * 64 + (p & 63)] = f2bf(v);
      }
    }
  }
}

// OUT: A=Ab [4096][1024], BT=WoT [1024][1024], O f32; grid (32, 8).
__global__ __launch_bounds__(256) void out_gemm128_k(const u16* __restrict__ A,
                                                     const u16* __restrict__ BT,
                                                     float* __restrict__ O) {
  int m0 = blockIdx.x * 128, n0 = blockIdx.y * 128;
  f32x4 acc[4][4];
  gemm128_core(A, BT, m0, n0, acc);
  int t = threadIdx.x, l = t & 63;
  int w = t >> 6, wm = w & 1, wn = w >> 1;
  int l15 = l & 15, q4 = l >> 4;
#pragma unroll
  for (int mi = 0; mi < 4; mi++) {
#pragma unroll
    for (int nt = 0; nt < 4; nt++) {
#pragma unroll
      for (int r = 0; r < 4; r++) {
        int m = m0 + wm * 64 + mi * 16 + q4 * 4 + r;
        int n = n0 + wn * 64 + nt * 16 + l15;
        O[(size_t)m * 1024 + n] = acc[mi][nt][r];
      }
    }
  }
}

// ---- flash attention: 32x32 swapped-QK^T, in-register softmax (T12) ----
__global__ __launch_bounds__(256) void attn_k(const u16* __restrict__ Q,
                                              const u16* __restrict__ K,
                                              const u16* __restrict__ VT2,
                                              u16* __restrict__ A) {
  __shared__ __align__(16) u16 Ks[2][64][64];
  __shared__ __align__(16) u16 Vs[2][64][64];
  __shared__ float rsbuf[4][32];
  int pr = blockIdx.x, h = blockIdx.y, b = blockIdx.z;
  int qt = b ? (15 - pr) : pr;
  size_t bh = (size_t)(b * 16 + h);
  const u16* Qp = Q + bh * 2048 * 64;
  const u16* Kp = K + bh * 2048 * 64;
  const u16* Vt = VT2 + bh * 32 * 64 * 64;   // [kt][d(64)][pc(64)]
  int t = threadIdx.x, l = t & 63, w = t >> 6;
  int l31 = l & 31, hi = l >> 5;
  int r8 = l >> 3, cs = ((l & 7) ^ r8) * 8;
  int swz = l31 & 7;
  const float NEG = -1e30f;
  int nkt = 2 * qt + 2;
  const u16* kbase = Kp + (size_t)(w * 16 + r8) * 64 + cs;
  const u16* vbase = Vt + (size_t)(w * 16 + r8) * 64 + cs;
  int qrow = qt * 128 + w * 32 + l31;

  bf16x8 qb[4];
#pragma unroll
  for (int kc = 0; kc < 4; kc++)
    qb[kc] = *reinterpret_cast<const bf16x8*>(Qp + (size_t)qrow * 64 + kc * 16 + hi * 8);

  f32x16 accO[2];
#pragma unroll
  for (int dh = 0; dh < 2; dh++)
#pragma unroll
    for (int r = 0; r < 16; r++) accO[dh][r] = 0.f;
  float rs = 0.f;

#pragma unroll
  for (int j = 0; j < 2; j++) {
    gload16(kbase + (size_t)(j * 512), &Ks[0][w * 16 + j * 8][0]);
    gload16(vbase + (size_t)(j * 512), &Vs[0][w * 16 + j * 8][0]);
  }
  __syncthreads();

  for (int kt = 0; kt < nkt; kt++) {
    int cur = kt & 1;
    if (kt < nkt - 1) {
      size_t off = (size_t)(kt + 1) * 4096;
#pragma unroll
      for (int j = 0; j < 2; j++) {
        gload16(kbase + off + j * 512, &Ks[cur ^ 1][w * 16 + j * 8][0]);
        gload16(vbase + off + j * 512, &Vs[cur ^ 1][w * 16 + j * 8][0]);
      }
    }

    f32x16 st[2];
#pragma unroll
    for (int kvh = 0; kvh < 2; kvh++)
#pragma unroll
      for (int r = 0; r < 16; r++) st[kvh][r] = 0.f;
    __builtin_amdgcn_s_setprio(1);
#pragma unroll
    for (int kc = 0; kc < 4; kc++) {
      bf16x8 ka0 = *reinterpret_cast<const bf16x8*>(
          &Ks[cur][l31][((2 * kc + hi) ^ swz) * 8]);
      bf16x8 ka1 = *reinterpret_cast<const bf16x8*>(
          &Ks[cur][32 + l31][((2 * kc + hi) ^ swz) * 8]);
      st[0] = __builtin_amdgcn_mfma_f32_32x32x16_bf16(ka0, qb[kc], st[0], 0, 0, 0);
      st[1] = __builtin_amdgcn_mfma_f32_32x32x16_bf16(ka1, qb[kc], st[1], 0, 0, 0);
    }
    __builtin_amdgcn_s_setprio(0);

    if (kt >= 2 * qt) {
      int kvb = kt * 64;
#pragma unroll
      for (int kvh = 0; kvh < 2; kvh++)
#pragma unroll
        for (int r = 0; r < 16; r++) {
          int kv = kvb + kvh * 32 + (r & 3) + 8 * (r >> 2) + 4 * hi;
          if (kv > qrow) st[kvh][r] = NEG;
        }
    }

#pragma unroll
    for (int kvh = 0; kvh < 2; kvh++)
#pragma unroll
      for (int r = 0; r < 16; r++) {
        float p = exp2f(st[kvh][r]);
        st[kvh][r] = p;
        rs += p;
      }

    bf16x8 pa[4];
#pragma unroll
    for (int ks = 0; ks < 4; ks++) {
      const f32x16& pp = st[ks >> 1];
      const int s8 = (ks & 1) * 8;
      uint32_t x0 = cvtpk(pp[s8 + 0], pp[s8 + 1]);
      uint32_t x1 = cvtpk(pp[s8 + 2], pp[s8 + 3]);
      uint32_t y0 = cvtpk(pp[s8 + 4], pp[s8 + 5]);
      uint32_t y1 = cvtpk(pp[s8 + 6], pp[s8 + 7]);
      pl32swap(x0, y0);
      pl32swap(x1, y1);
      uint32_t wds[4] = {x0, x1, y0, y1};
      pa[ks] = *reinterpret_cast<const bf16x8*>(wds);
    }

    __builtin_amdgcn_s_setprio(1);
#pragma unroll
    for (int dh = 0; dh < 2; dh++)
#pragma unroll
      for (int ks = 0; ks < 4; ks++) {
        bf16x8 vb = *reinterpret_cast<const bf16x8*>(
            &Vs[cur][dh * 32 + l31][((2 * ks + hi) ^ swz) * 8]);
        accO[dh] = __builtin_amdgcn_mfma_f32_32x32x16_bf16(pa[ks], vb, accO[dh], 0, 0, 0);
      }
    __builtin_amdgcn_s_setprio(0);
    __syncthreads();
  }

  rs += __shfl_xor(rs, 32, 64);
  if (hi == 0) rsbuf[w][l31] = rs;
  __syncthreads();
#pragma unroll
  for (int r = 0; r < 16; r++) {
    int ql = (r & 3) + 8 * (r >> 2) + 4 * hi;
    float inv = 1.f / rsbuf[w][ql];
    int prow = qt * 128 + w * 32 + ql;
    size_t base = ((size_t)(b * 2048 + prow)) * 1024 + h * 64;
    A[base + l31] = f2bf(accO[0][r] * inv);
    A[base + 32 + l31] = f2bf(accO[1][r] * inv);
  }
}

extern "C" void kernel_launch(void* const* d_in, const int* in_sizes, int n_in,
                              void* d_out, int out_size, void* d_ws, size_t ws_size,
                              hipStream_t stream) {
  const float* X  = (const float*)d_in[0];  // residual_stream [2][2048][1024]
  const float* Wq = (const float*)d_in[1];  // weight_query [16][1024][64]
  const float* Wk = (const float*)d_in[2];  // weight_key   [16][1024][64]
  const float* Wv = (const float*)d_in[3];  // weight_value [16][1024][64]
  const float* Wo = (const float*)d_in[4];  // weight_out   [1024][1024]
  float* out = (float*)d_out;               // [2][2048][1024] f32

  u16* ws = (u16*)d_ws;
  u16* WqT = ws;                    // [16][64][1024] x3 contiguous
  u16* WoT = WqT + 3145728;         // [1024][1024]
  u16* Xb  = WoT + 1048576;         // [4096][1024] bf16 (dead after qkv)
  u16* Qb  = Xb + 4194304;          // [32][2048][64]
  u16* Kb  = Qb + 4194304;          // [32][2048][64]
  u16* VT2 = Kb + 4194304;          // [32][32][64][64] tile-blocked
  u16* Ab  = Xb;                    // aliases Xb; total 40 MB

  xcvt_k<<<dim3(2048), 256, 0, stream>>>(X, Xb);
  transpose_qkv_k<<<dim3(16, 1, 48), 256, 0, stream>>>(Wq, Wk, Wv, WqT);
  transpose_cvt_k<<<dim3(16, 16, 1), 256, 0, stream>>>(Wo, WoT, 1024, 1024);

  qkv_gemm256_k<<<dim3(16, 12), 512, 131072, stream>>>(Xb, WqT, Qb, Kb, VT2);
  attn_k<<<dim3(16, 16, 2), 256, 0, stream>>>(Qb, Kb, VT2, Ab);
  out_gemm128_k<<<dim3(32, 8), 256, 0, stream>>>(Ab, WoT, out);
}